// Round 6
// baseline (55361.255 us; speedup 1.0000x reference)
//
#include <hip/hip_runtime.h>
#include <hip/hip_cooperative_groups.h>
#include <math.h>

namespace cg = cooperative_groups;

#define TSTEPS 1024
#define NITER  1026

// ---- ws layout (float offsets) ----
// W1L [128 cu][4 kq][128 k][8 jrow]  (jrow = jj*4+g; k = concat(h0, h1-prev))
// W0L [128 cu][4 kq][64 k][8]        (recurrent h0 weights)
// W0X [128 cu][4 kq][4 k][8]         (x weights)
// FCW [256 k][256 f]                 (fc1w transposed)
// BS1/BS0 [128 cu][8 jrow]           (summed biases)
// H0T/H1T [2 parity][256 k][256 r]   (transposed hidden states)
#define OFF_W1L 0u
#define OFF_W0L 524288u
#define OFF_W0X 786432u
#define OFF_FCW 802816u
#define OFF_BS1 868352u
#define OFF_BS0 869376u
#define OFF_H0T 870400u
#define OFF_H1T 1001472u
#define WS_END  1132544u

__device__ __forceinline__ float fast_sigmoid(float v) {
    return __builtin_amdgcn_rcpf(1.0f + __expf(-v));
}
__device__ __forceinline__ float fast_tanh(float v) {
    return 1.0f - 2.0f * __builtin_amdgcn_rcpf(1.0f + __expf(2.0f * v));
}

__global__ __launch_bounds__(256) void prep_kernel(
    const float* __restrict__ Wih0, const float* __restrict__ Whh0,
    const float* __restrict__ bih0, const float* __restrict__ bhh0,
    const float* __restrict__ Wih1, const float* __restrict__ Whh1,
    const float* __restrict__ bih1, const float* __restrict__ bhh1,
    const float* __restrict__ fc1w,
    float* __restrict__ ws)
{
    for (unsigned idx = blockIdx.x * blockDim.x + threadIdx.x; idx < WS_END;
         idx += gridDim.x * blockDim.x) {
        float v = 0.0f;
        if (idx < OFF_W0L) {                      // W1L
            unsigned cu = idx >> 12, rem = idx & 4095u;
            unsigned kq = rem >> 10, rem2 = rem & 1023u;
            unsigned k = rem2 >> 3, jrow = rem2 & 7u;
            unsigned grow = (jrow & 3u) * 256u + 2u * cu + (jrow >> 2);
            unsigned kg = kq * 128u + k;
            v = (kg < 256u) ? Wih1[grow * 256u + kg] : Whh1[grow * 256u + kg - 256u];
        } else if (idx < OFF_W0X) {               // W0L
            unsigned i2 = idx - OFF_W0L;
            unsigned cu = i2 >> 11, rem = i2 & 2047u;
            unsigned kq = rem >> 9, rem2 = rem & 511u;
            unsigned k = rem2 >> 3, jrow = rem2 & 7u;
            unsigned grow = (jrow & 3u) * 256u + 2u * cu + (jrow >> 2);
            v = Whh0[grow * 256u + kq * 64u + k];
        } else if (idx < OFF_FCW) {               // W0X
            unsigned i2 = idx - OFF_W0X;
            unsigned cu = i2 >> 7, rem = i2 & 127u;
            unsigned kq = rem >> 5, rem2 = rem & 31u;
            unsigned k = rem2 >> 3, jrow = rem2 & 7u;
            unsigned grow = (jrow & 3u) * 256u + 2u * cu + (jrow >> 2);
            v = Wih0[grow * 16u + kq * 4u + k];
        } else if (idx < OFF_BS1) {               // FCW (fc1w^T)
            unsigned i2 = idx - OFF_FCW;
            unsigned k = i2 >> 8, f = i2 & 255u;
            v = fc1w[f * 256u + k];
        } else if (idx < OFF_BS0) {               // BS1
            unsigned i2 = idx - OFF_BS1;
            unsigned cu = i2 >> 3, jrow = i2 & 7u;
            unsigned grow = (jrow & 3u) * 256u + 2u * cu + (jrow >> 2);
            v = bih1[grow] + bhh1[grow];
        } else if (idx < OFF_H0T) {               // BS0
            unsigned i2 = idx - OFF_BS0;
            unsigned cu = i2 >> 3, jrow = i2 & 7u;
            unsigned grow = (jrow & 3u) * 256u + 2u * cu + (jrow >> 2);
            v = bih0[grow] + bhh0[grow];
        }                                          // else: zero h buffers
        ws[idx] = v;
    }
}

// load 32 consecutive-k h values for this lane's row r (coalesced: lane = r)
#define LD32(DST, SRC, C, R) do { \
    _Pragma("unroll") \
    for (int kk_ = 0; kk_ < 32; ++kk_) DST[kk_] = (SRC)[((C) * 32 + kk_) * 256 + (R)]; \
  } while (0)

// 32-k x 8-gate-row dot, weights broadcast from LDS ([k][8] layout)
#define DOT32(ACC, HV, WB) do { \
    _Pragma("unroll") \
    for (int kk_ = 0; kk_ < 32; ++kk_) { \
        const float h_ = HV[kk_]; \
        const float4 wa_ = *(const float4*)&(WB)[kk_ * 8]; \
        const float4 wb_ = *(const float4*)&(WB)[kk_ * 8 + 4]; \
        ACC[0] = fmaf(h_, wa_.x, ACC[0]); ACC[1] = fmaf(h_, wa_.y, ACC[1]); \
        ACC[2] = fmaf(h_, wa_.z, ACC[2]); ACC[3] = fmaf(h_, wa_.w, ACC[3]); \
        ACC[4] = fmaf(h_, wb_.x, ACC[4]); ACC[5] = fmaf(h_, wb_.y, ACC[5]); \
        ACC[6] = fmaf(h_, wb_.z, ACC[6]); ACC[7] = fmaf(h_, wb_.w, ACC[7]); \
    } \
  } while (0)

// Persistent pipelined kernel. 256 blocks x 1024 threads, 1 block/CU.
//   blocks [0,128)   : L1 LSTM step i-1 (2 hidden units; 16 waves = 4 rg x 4 kq)
//   blocks [128,256) : L0 LSTM step i   (same shape, K=256+16)
//   blocks [128,160) : + FC (fc1+relu+fc2) for step i-2, 8 batch rows each
__global__ __launch_bounds__(1024, 4) void lstm_persist(
    const float* __restrict__ x,
    const float* __restrict__ fc1b, const float* __restrict__ fc2w,
    const float* __restrict__ fc2b,
    const float* __restrict__ wro, float* __restrict__ hrw,
    float* __restrict__ out)
{
    cg::grid_group grid = cg::this_grid();
    __shared__ __align__(16) float wl[4352];      // weights (stationary all steps)
    __shared__ __align__(16) float red[6144];     // kq-partial exchange
    __shared__ __align__(16) float fcred[4096];   // FC khalf exchange

    const int tid  = threadIdx.x;
    const int lane = tid & 63;
    const int wv   = __builtin_amdgcn_readfirstlane(tid >> 6);  // 0..15
    const int rg   = wv & 3, kq = wv >> 2;
    const bool isL1 = (blockIdx.x < 128);
    const int cu   = blockIdx.x & 127;
    const int r    = rg * 64 + lane;

    float* h0a = hrw + OFF_H0T;
    float* h1a = hrw + OFF_H1T;

    // ---- stage stationary weights into LDS (once) ----
    if (isL1) {
        for (int i = tid; i < 4096; i += 1024) wl[i] = wro[OFF_W1L + cu * 4096 + i];
    } else {
        for (int i = tid; i < 2048; i += 1024) wl[i] = wro[OFF_W0L + cu * 2048 + i];
        if (tid < 128) wl[2048 + tid] = wro[OFF_W0X + cu * 128 + tid];
    }
    float bsv[8];
    {
        const float* bp = wro + (isL1 ? OFF_BS1 : OFF_BS0) + cu * 8;
        #pragma unroll
        for (int j2 = 0; j2 < 8; ++j2) bsv[j2] = bp[j2];
    }
    const bool fcb = (!isL1) && (cu < 32);
    const int frr = wv >> 1, fkh = wv & 1;
    const int fr  = cu * 8 + frr;
    float4 f1b = {0, 0, 0, 0}, f2w = {0, 0, 0, 0};
    float f2b0 = 0.f;
    if (fcb) {
        f1b  = *(const float4*)&fc1b[lane * 4];
        f2w  = *(const float4*)&fc2w[lane * 4];
        f2b0 = fc2b[0];
    }
    float c0 = 0.f, c1 = 0.f;   // cell state: registers for the whole sequence
    __syncthreads();

    #pragma unroll 1
    for (int i = 0; i < NITER; ++i) {
        if (isL1) {
            const int s = i - 1;
            const bool act = (s >= 0) && (s < TSTEPS);
            float a[8] = {0, 0, 0, 0, 0, 0, 0, 0};
            if (act) {
                // kq 0,1 -> h0(s) [written last iter]; kq 2,3 -> h1(s-1)
                const float* hsrc = (kq < 2)
                    ? (h0a + (s & 1) * 65536 + kq * 32768)
                    : (h1a + ((s + 1) & 1) * 65536 + (kq - 2) * 32768);
                const float* wq = &wl[kq * 1024];
                float hA[32], hB[32];
                LD32(hA, hsrc, 0, r);
                LD32(hB, hsrc, 1, r);
                DOT32(a, hA, wq);
                LD32(hA, hsrc, 2, r);
                DOT32(a, hB, wq + 256);
                LD32(hB, hsrc, 3, r);
                DOT32(a, hA, wq + 512);
                DOT32(a, hB, wq + 768);
                if (kq != 0) {
                    #pragma unroll
                    for (int j2 = 0; j2 < 8; ++j2)
                        red[((kq - 1) * 4 + rg) * 512 + j2 * 64 + lane] = a[j2];
                }
            }
            __syncthreads();
            if (act && kq == 0) {
                #pragma unroll
                for (int j2 = 0; j2 < 8; ++j2)
                    a[j2] += red[rg * 512 + j2 * 64 + lane]
                           + red[(4 + rg) * 512 + j2 * 64 + lane]
                           + red[(8 + rg) * 512 + j2 * 64 + lane];
                float* hdst = h1a + (s & 1) * 65536 + (2 * cu) * 256 + r;
                {
                    float ig = fast_sigmoid(a[0] + bsv[0]);
                    float fg = fast_sigmoid(a[1] + bsv[1]);
                    float gg = fast_tanh   (a[2] + bsv[2]);
                    float og = fast_sigmoid(a[3] + bsv[3]);
                    c0 = fg * c0 + ig * gg;
                    hdst[0] = og * fast_tanh(c0);
                }
                {
                    float ig = fast_sigmoid(a[4] + bsv[4]);
                    float fg = fast_sigmoid(a[5] + bsv[5]);
                    float gg = fast_tanh   (a[6] + bsv[6]);
                    float og = fast_sigmoid(a[7] + bsv[7]);
                    c1 = fg * c1 + ig * gg;
                    hdst[256] = og * fast_tanh(c1);
                }
            }
        } else {
            const bool act = (i < TSTEPS);
            float a[8] = {0, 0, 0, 0, 0, 0, 0, 0};
            if (act) {
                const float* hsrc = h0a + ((i + 1) & 1) * 65536 + kq * 16384; // h0(i-1)
                const float* wq = &wl[kq * 512];
                float hA[32], hB[32];
                LD32(hA, hsrc, 0, r);
                LD32(hB, hsrc, 1, r);
                DOT32(a, hA, wq);
                DOT32(a, hB, wq + 256);
                // x projection: 4 k of x_t per kq
                const float4 xv = *(const float4*)(x + ((size_t)r * TSTEPS + i) * 16 + kq * 4);
                const float* wx = &wl[2048 + kq * 32];
                const float xs[4] = {xv.x, xv.y, xv.z, xv.w};
                #pragma unroll
                for (int k4 = 0; k4 < 4; ++k4) {
                    const float4 wa = *(const float4*)&wx[k4 * 8];
                    const float4 wb = *(const float4*)&wx[k4 * 8 + 4];
                    a[0] = fmaf(xs[k4], wa.x, a[0]); a[1] = fmaf(xs[k4], wa.y, a[1]);
                    a[2] = fmaf(xs[k4], wa.z, a[2]); a[3] = fmaf(xs[k4], wa.w, a[3]);
                    a[4] = fmaf(xs[k4], wb.x, a[4]); a[5] = fmaf(xs[k4], wb.y, a[5]);
                    a[6] = fmaf(xs[k4], wb.z, a[6]); a[7] = fmaf(xs[k4], wb.w, a[7]);
                }
                if (kq != 0) {
                    #pragma unroll
                    for (int j2 = 0; j2 < 8; ++j2)
                        red[((kq - 1) * 4 + rg) * 512 + j2 * 64 + lane] = a[j2];
                }
            }
            // FC gemv for step i-2 (fc blocks only; all 16 waves: 8 r x 2 k-halves)
            const bool fact = fcb && (i >= 2);
            float fa[4] = {0, 0, 0, 0};
            if (fact) {
                const float* hcol = h1a + (i & 1) * 65536 + fkh * 32768 + fr;
                const float* fw = wro + OFF_FCW + fkh * 32768;
                #pragma unroll 8
                for (int kk = 0; kk < 128; ++kk) {
                    const float hv = hcol[kk * 256];
                    const float4 w4 = *(const float4*)&fw[kk * 256 + lane * 4];
                    fa[0] = fmaf(hv, w4.x, fa[0]);
                    fa[1] = fmaf(hv, w4.y, fa[1]);
                    fa[2] = fmaf(hv, w4.z, fa[2]);
                    fa[3] = fmaf(hv, w4.w, fa[3]);
                }
                *(float4*)&fcred[(frr * 2 + fkh) * 256 + lane * 4] = *(float4*)fa;
            }
            __syncthreads();
            if (act && kq == 0) {
                #pragma unroll
                for (int j2 = 0; j2 < 8; ++j2)
                    a[j2] += red[rg * 512 + j2 * 64 + lane]
                           + red[(4 + rg) * 512 + j2 * 64 + lane]
                           + red[(8 + rg) * 512 + j2 * 64 + lane];
                float* hdst = h0a + (i & 1) * 65536 + (2 * cu) * 256 + r;
                {
                    float ig = fast_sigmoid(a[0] + bsv[0]);
                    float fg = fast_sigmoid(a[1] + bsv[1]);
                    float gg = fast_tanh   (a[2] + bsv[2]);
                    float og = fast_sigmoid(a[3] + bsv[3]);
                    c0 = fg * c0 + ig * gg;
                    hdst[0] = og * fast_tanh(c0);
                }
                {
                    float ig = fast_sigmoid(a[4] + bsv[4]);
                    float fg = fast_sigmoid(a[5] + bsv[5]);
                    float gg = fast_tanh   (a[6] + bsv[6]);
                    float og = fast_sigmoid(a[7] + bsv[7]);
                    c1 = fg * c1 + ig * gg;
                    hdst[256] = og * fast_tanh(c1);
                }
            }
            if (fact && fkh == 0) {
                const float4 va = *(const float4*)&fcred[(frr * 2) * 256 + lane * 4];
                const float4 vb = *(const float4*)&fcred[(frr * 2 + 1) * 256 + lane * 4];
                float p = 0.f;
                { float v = va.x + vb.x + f1b.x; v = v > 0.f ? v : 0.f; p = fmaf(v, f2w.x, p); }
                { float v = va.y + vb.y + f1b.y; v = v > 0.f ? v : 0.f; p = fmaf(v, f2w.y, p); }
                { float v = va.z + vb.z + f1b.z; v = v > 0.f ? v : 0.f; p = fmaf(v, f2w.z, p); }
                { float v = va.w + vb.w + f1b.w; v = v > 0.f ? v : 0.f; p = fmaf(v, f2w.w, p); }
                #pragma unroll
                for (int m = 1; m < 64; m <<= 1) p += __shfl_xor(p, m);
                if (lane == 0) out[(size_t)fr * TSTEPS + (i - 2)] = p + f2b0;
            }
        }
        grid.sync();
    }
}

extern "C" void kernel_launch(void* const* d_in, const int* in_sizes, int n_in,
                              void* d_out, int out_size, void* d_ws, size_t ws_size,
                              hipStream_t stream)
{
    const float* x    = (const float*)d_in[0];
    const float* Wih0 = (const float*)d_in[1];
    const float* Whh0 = (const float*)d_in[2];
    const float* bih0 = (const float*)d_in[3];
    const float* bhh0 = (const float*)d_in[4];
    const float* Wih1 = (const float*)d_in[5];
    const float* Whh1 = (const float*)d_in[6];
    const float* bih1 = (const float*)d_in[7];
    const float* bhh1 = (const float*)d_in[8];
    const float* fc1w = (const float*)d_in[9];
    const float* fc1b = (const float*)d_in[10];
    const float* fc2w = (const float*)d_in[11];
    const float* fc2b = (const float*)d_in[12];
    float* ws  = (float*)d_ws;
    float* out = (float*)d_out;

    prep_kernel<<<512, 256, 0, stream>>>(Wih0, Whh0, bih0, bhh0,
                                         Wih1, Whh1, bih1, bhh1, fc1w, ws);

    void* args[] = {(void*)&x, (void*)&fc1b, (void*)&fc2w, (void*)&fc2b,
                    (void*)&ws, (void*)&ws, (void*)&out};
    hipLaunchCooperativeKernel((const void*)lstm_persist, dim3(256), dim3(1024),
                               args, 0, stream);
}